// Round 8
// baseline (168.657 us; speedup 1.0000x reference)
//
#include <hip/hip_runtime.h>

// B=16, C=256, O=256, H=W=64, T_DIM=512, E=4, K=3
typedef __bf16 bf16x8 __attribute__((ext_vector_type(8)));
typedef float f32x4 __attribute__((ext_vector_type(4)));

__device__ __forceinline__ unsigned short f2bf(float f) {
  union { float f; unsigned int u; } v;
  v.f = f;
  unsigned int r = v.u + 0x7FFFu + ((v.u >> 16) & 1u);  // RNE
  return (unsigned short)(r >> 16);
}

__device__ __forceinline__ void load_lds16(const void* g, void* l) {
  __builtin_amdgcn_global_load_lds(
      (__attribute__((address_space(1))) void*)(void*)g,
      (__attribute__((address_space(3))) void*)l, 16, 0, 0);
}

// ---------- transpose + pad + pooled partials ----------
__global__ void transpose_kernel(const float* __restrict__ x, unsigned short* __restrict__ xTpad,
                                 float* __restrict__ part) {
  int bid = blockIdx.x;
  int b = bid / 66, hp = bid % 66;
  unsigned short* rowbase = xTpad + ((size_t)(b * 66 + hp)) * 66 * 256;
  int t = threadIdx.x;
  if (hp == 0 || hp == 65) {
    uint4 z = make_uint4(0u, 0u, 0u, 0u);
    for (int i = t; i < 2112; i += 256) ((uint4*)rowbase)[i] = z;
    return;
  }
  int h = hp - 1;
  __shared__ unsigned short lds[64][264];
  __shared__ float psum[256];
  const float* xb = x + ((size_t)b * 256 * 64 + h) * 64;
  int lane = t & 63;
  #pragma unroll
  for (int g = 0; g < 16; ++g) {
    int c = g * 16 + (t >> 4);
    int w0 = (t & 15) * 4;
    float4 v = *(const float4*)&xb[(size_t)c * 4096 + w0];
    lds[w0 + 0][c] = f2bf(v.x);
    lds[w0 + 1][c] = f2bf(v.y);
    lds[w0 + 2][c] = f2bf(v.z);
    lds[w0 + 3][c] = f2bf(v.w);
    float s = v.x + v.y + v.z + v.w;
    s += __shfl_xor(s, 1); s += __shfl_xor(s, 2);
    s += __shfl_xor(s, 4); s += __shfl_xor(s, 8);
    if ((lane & 15) == 0) psum[c] = s;
  }
  __syncthreads();
  #pragma unroll
  for (int p = 0; p < 8; ++p) {
    int w = p * 8 + (t >> 5);
    int seg = t & 31;
    uint4 u = *(const uint4*)&lds[w][seg * 8];
    *(uint4*)&rowbase[(w + 1) * 256 + seg * 8] = u;
  }
  if (t < 64) {
    uint4 z = make_uint4(0u, 0u, 0u, 0u);
    int row = (t >> 5) ? 65 : 0;
    *(uint4*)&rowbase[row * 256 + (t & 31) * 8] = z;
  }
  if (t < 256) part[((size_t)b * 64 + h) * 256 + t] = psum[t];
}

// ---------- router (fp32 exact), 512 threads ----------
__global__ void router_kernel(
    const float* __restrict__ time_emb, const float* __restrict__ part,
    const float* __restrict__ Wq, const float* __restrict__ bq,
    const float* __restrict__ Wk, const float* __restrict__ bk,
    const float* __restrict__ Wv, const float* __restrict__ bv,
    const float* __restrict__ Wm1, const float* __restrict__ bm1,
    const float* __restrict__ Wm2, const float* __restrict__ bm2,
    const float* __restrict__ Wc, const float* __restrict__ bc,
    const float* __restrict__ expert_b,
    float* __restrict__ rw_out, float* __restrict__ beff_out) {
  int b = blockIdx.x, tid = threadIdx.x;
  int t = tid & 255;
  __shared__ float te[512], pl[256], qs[256], xa[256], m1s[64], xms[256], rws[4];
  te[tid] = time_emb[b * 512 + tid];
  if (tid < 256) {
    float s = 0.f;
    const float* pp = part + (size_t)b * 16384 + tid;
    for (int hh = 0; hh < 64; ++hh) s += pp[hh * 256];
    pl[tid] = s * (1.0f / 4096.0f);
  }
  __syncthreads();
  if (tid < 256) {
    float q = bq[t];
    const float4* wq4 = (const float4*)(Wq + (size_t)t * 512);
    #pragma unroll 4
    for (int i = 0; i < 128; ++i) {
      float4 w4 = wq4[i];
      q += w4.x * te[i*4] + w4.y * te[i*4+1] + w4.z * te[i*4+2] + w4.w * te[i*4+3];
    }
    qs[t] = q;
  } else {
    float k = bk[t], v = bv[t];
    const float4* wk4 = (const float4*)(Wk + (size_t)t * 256);
    const float4* wv4 = (const float4*)(Wv + (size_t)t * 256);
    #pragma unroll 4
    for (int i = 0; i < 64; ++i) {
      float4 a4 = wk4[i], b4 = wv4[i];
      float p0 = pl[i*4], p1 = pl[i*4+1], p2 = pl[i*4+2], p3 = pl[i*4+3];
      k += a4.x * p0 + a4.y * p1 + a4.z * p2 + a4.w * p3;
      v += b4.x * p0 + b4.y * p1 + b4.z * p2 + b4.w * p3;
    }
    xa[t] = k;
    xms[t] = v;
  }
  __syncthreads();
  if (tid < 256) {
    float k = xa[t], v = xms[t];
    float attn = 1.0f / (1.0f + expf(-(qs[t] * k)));
    qs[t] = v * attn;
  }
  __syncthreads();
  if (tid < 64) {
    float s = bm1[tid];
    const float4* w1 = (const float4*)(Wm1 + (size_t)tid * 256);
    #pragma unroll 4
    for (int i = 0; i < 64; ++i) {
      float4 w4 = w1[i];
      s += w4.x * qs[i*4] + w4.y * qs[i*4+1] + w4.z * qs[i*4+2] + w4.w * qs[i*4+3];
    }
    m1s[tid] = 0.5f * s * (1.0f + erff(s * 0.7071067811865476f));
  }
  __syncthreads();
  if (tid < 256) {
    float hsum = bm2[t];
    const float* w2 = Wm2 + (size_t)t * 64;
    for (int j = 0; j < 64; ++j) hsum += m1s[j] * w2[j];
    xms[t] = qs[t] + hsum;
  }
  __syncthreads();
  if (tid < 4) {
    float s = bc[tid];
    const float* wc = Wc + (size_t)tid * 256;
    for (int i = 0; i < 256; ++i) s += xms[i] * wc[i];
    float r = tanhf(s);
    rws[tid] = r;
    rw_out[b * 4 + tid] = r;
  }
  __syncthreads();
  if (tid < 256) {
    float be = 0.f;
    #pragma unroll
    for (int e = 0; e < 4; ++e) be += rws[e] * expert_b[e * 256 + t];
    beff_out[b * 256 + t] = be;
  }
}

// ---------- expert mix -> wmix[b][o][k], k = tap*256 + c (round-6 coalesced) ----------
__global__ void wmix_kernel(const float* __restrict__ ew, const float* __restrict__ rw,
                            unsigned short* __restrict__ wmix) {
  int o = blockIdx.x, t = threadIdx.x;
  __shared__ float lew[4][2304];
  __shared__ float rsh[64];
  if (t < 64) rsh[t] = rw[t];
  #pragma unroll
  for (int e = 0; e < 4; ++e) {
    const float* s = ew + ((size_t)e * 256 + o) * 2304;
    #pragma unroll
    for (int j = 0; j < 9; ++j) lew[e][j * 256 + t] = s[j * 256 + t];
  }
  __syncthreads();
  float wv[4][9];
  #pragma unroll
  for (int e = 0; e < 4; ++e)
    #pragma unroll
    for (int tt = 0; tt < 9; ++tt) wv[e][tt] = lew[e][t * 9 + tt];
  for (int b = 0; b < 16; ++b) {
    float r0 = rsh[b*4], r1 = rsh[b*4+1], r2 = rsh[b*4+2], r3 = rsh[b*4+3];
    unsigned short* wo = wmix + ((size_t)b * 256 + o) * 2304 + t;
    #pragma unroll
    for (int tt = 0; tt < 9; ++tt) {
      float m = r0 * wv[0][tt] + r1 * wv[1][tt] + r2 * wv[2][tt] + r3 * wv[3][tt];
      wo[tt * 256] = f2bf(m);
    }
  }
}

// ---------- conv: per-sample GEMM, 512 blocks x 4 waves (2 blocks/CU) ----------
// Block tile 256M x 128N, wave = 64M x 128N (4M x 1N). A gathered direct
// global->VGPR from linear wmix (16 full cachelines per load); B in LDS
// [2][128][64] (32 KB) pre-swizzled gll + XOR ds_read. Per tile: 4 gll (B t+1)
// | sched_barrier | 8 A loads (t+1) | 16 ds_read + 64 MFMA | vmcnt(8) | barrier.
__global__ __launch_bounds__(256, 2) void conv_kernel(
    const unsigned short* __restrict__ xT, const unsigned short* __restrict__ wmix,
    const float* __restrict__ beff, float* __restrict__ out) {
  __shared__ unsigned short Bs[2][8192];
  int bid = blockIdx.x;
  int b = ((bid & 7) << 1) | ((bid >> 8) & 1);   // same b -> same XCD
  int nt = (bid >> 3) & 31;
  int h0 = nt << 1;                               // 2 output h-rows per block
  int tid = threadIdx.x;
  int wid = tid >> 6, lane = tid & 63;            // wid = wave's M quarter
  int lm = lane & 15, lg = lane >> 4;

  const unsigned short* xTb = xT + (size_t)b * 66 * 66 * 256;
  const unsigned short* wmb = wmix + (size_t)b * 256 * 2304;
  // per-lane A gather base: row = wid*64 + lm (+mf*16), k offset lg*8 (+kbase)
  const unsigned short* wmA = wmb + (size_t)(wid * 64 + lm) * 2304 + lg * 8;

  // staging lane constants (pre-swizzled source slot)
  int lr = lane >> 3;
  int slot_g = (lane & 7) ^ lr;
  int b_lane = lr * 256 + slot_g * 8;

  // read-side swizzled k-slot offsets (ushorts)
  int sw0 = ((0 + lg) ^ (lm & 7)) * 8;
  int sw1 = ((4 + lg) ^ (lm & 7)) * 8;

  // stage B rows wid*32 + j*8 .. +7  (j = 0..3), n-row r: q=r>>6 (h), w=r&63
  auto stB = [&](int buf, int kh, int cc, int kw, int j) {
    int r0 = wid * 32 + j * 8;
    int q = r0 >> 6, w0 = r0 & 63;
    const unsigned short* src =
        xTb + (size_t)((h0 + q + kh) * 66 + w0 + kw) * 256 + cc * 64 + b_lane;
    load_lds16(src, &Bs[buf][r0 * 64]);
  };

  f32x4 acc[4][8];
  #pragma unroll
  for (int mf = 0; mf < 4; ++mf)
    #pragma unroll
    for (int nf = 0; nf < 8; ++nf)
      acc[mf][nf] = (f32x4){0.f, 0.f, 0.f, 0.f};

  bf16x8 Ae[4][2], Ao[4][2];

  // prologue: tile 0 = (kh0, cc0, kw0)
  stB(0, 0, 0, 0, 0); stB(0, 0, 0, 0, 1); stB(0, 0, 0, 0, 2); stB(0, 0, 0, 0, 3);
  __builtin_amdgcn_sched_barrier(0);
  #pragma unroll
  for (int mf = 0; mf < 4; ++mf)
    #pragma unroll
    for (int kk = 0; kk < 2; ++kk)
      Ae[mf][kk] = *(const bf16x8*)(wmA + (size_t)(mf * 16) * 2304 + kk * 32);
  asm volatile("s_waitcnt vmcnt(8)" ::: "memory");
  __builtin_amdgcn_s_barrier();

  auto tile_body = [&](int t, int buf, bf16x8 (&Acur)[4][2], bf16x8 (&Anext)[4][2])
      __attribute__((always_inline)) {
    bool st = (t < 35);
    if (st) {
      int tn = t + 1;
      int khn = tn / 12, rn = tn % 12, ccn = rn / 3, kwn = rn % 3;
      stB(buf ^ 1, khn, ccn, kwn, 0); stB(buf ^ 1, khn, ccn, kwn, 1);
      stB(buf ^ 1, khn, ccn, kwn, 2); stB(buf ^ 1, khn, ccn, kwn, 3);
      __builtin_amdgcn_sched_barrier(0);   // keep gll ahead of A-loads in vmcnt FIFO
      int kbase = (khn * 3 + kwn) * 256 + ccn * 64;
      #pragma unroll
      for (int mf = 0; mf < 4; ++mf)
        #pragma unroll
        for (int kk = 0; kk < 2; ++kk)
          Anext[mf][kk] = *(const bf16x8*)(wmA + (size_t)(mf * 16) * 2304 + kbase + kk * 32);
    }
    // 16 ds_read + 64 MFMA, per-nf interleave (compiler pipelines counted lgkm)
    #pragma unroll
    for (int nf = 0; nf < 8; ++nf) {
      bf16x8 b0 = *(const bf16x8*)&Bs[buf][(nf * 16 + lm) * 64 + sw0];
      bf16x8 b1 = *(const bf16x8*)&Bs[buf][(nf * 16 + lm) * 64 + sw1];
      #pragma unroll
      for (int mf = 0; mf < 4; ++mf) {
        acc[mf][nf] = __builtin_amdgcn_mfma_f32_16x16x32_bf16(Acur[mf][0], b0, acc[mf][nf], 0, 0, 0);
        acc[mf][nf] = __builtin_amdgcn_mfma_f32_16x16x32_bf16(Acur[mf][1], b1, acc[mf][nf], 0, 0, 0);
      }
    }
    if (st) {
      asm volatile("s_waitcnt vmcnt(8)" ::: "memory");   // 4 gll (t+1) landed; A in flight
      __builtin_amdgcn_s_barrier();
    }
  };

  for (int i = 0; i < 18; ++i) {
    tile_body(2 * i, 0, Ae, Ao);
    tile_body(2 * i + 1, 1, Ao, Ae);
  }

  // epilogue: D row (o) = lg*4 + reg, col (n) = lm
  #pragma unroll
  for (int mf = 0; mf < 4; ++mf) {
    int o = wid * 64 + mf * 16 + lg * 4;
    float be0 = beff[b * 256 + o + 0];
    float be1 = beff[b * 256 + o + 1];
    float be2 = beff[b * 256 + o + 2];
    float be3 = beff[b * 256 + o + 3];
    #pragma unroll
    for (int nf = 0; nf < 8; ++nf) {
      int n = nf * 16 + lm;
      int hh = h0 + (n >> 6), w = n & 63;
      float* op = out + (((size_t)(b * 256 + o)) * 64 + hh) * 64 + w;
      op[0]            = acc[mf][nf][0] + be0;
      op[4096]         = acc[mf][nf][1] + be1;
      op[2 * 4096]     = acc[mf][nf][2] + be2;
      op[3 * 4096]     = acc[mf][nf][3] + be3;
    }
  }
}

extern "C" void kernel_launch(void* const* d_in, const int* in_sizes, int n_in,
                              void* d_out, int out_size, void* d_ws, size_t ws_size,
                              hipStream_t stream) {
  const float* x        = (const float*)d_in[0];
  const float* time_emb = (const float*)d_in[1];
  const float* Wq = (const float*)d_in[2];
  const float* bq = (const float*)d_in[3];
  const float* Wk = (const float*)d_in[4];
  const float* bk = (const float*)d_in[5];
  const float* Wv = (const float*)d_in[6];
  const float* bv = (const float*)d_in[7];
  const float* Wm1 = (const float*)d_in[8];
  const float* bm1 = (const float*)d_in[9];
  const float* Wm2 = (const float*)d_in[10];
  const float* bm2 = (const float*)d_in[11];
  const float* Wc = (const float*)d_in[12];
  const float* bc = (const float*)d_in[13];
  const float* expert_w = (const float*)d_in[14];
  const float* expert_b = (const float*)d_in[15];
  float* out = (float*)d_out;

  char* ws = (char*)d_ws;
  float* rw   = (float*)(ws + 0);
  float* beff = (float*)(ws + 1024);
  float* part = (float*)(ws + 20480);
  unsigned short* xTpad = (unsigned short*)(ws + 1069056);             // 35.7 MB
  unsigned short* wmix  = (unsigned short*)(ws + 1069056 + 35684352);  // 18.9 MB

  transpose_kernel<<<1056, 256, 0, stream>>>(x, xTpad, part);
  router_kernel<<<16, 512, 0, stream>>>(time_emb, part, Wq, bq, Wk, bk, Wv, bv,
                                        Wm1, bm1, Wm2, bm2, Wc, bc, expert_b, rw, beff);
  wmix_kernel<<<256, 256, 0, stream>>>(expert_w, rw, wmix);
  conv_kernel<<<512, 256, 0, stream>>>(xTpad, wmix, beff, out);
}

// Round 9
// 154.937 us; speedup vs baseline: 1.0886x; 1.0886x over previous
//
#include <hip/hip_runtime.h>

// B=16, C=256, O=256, H=W=64, T_DIM=512, E=4, K=3
typedef __bf16 bf16x8 __attribute__((ext_vector_type(8)));
typedef float f32x4 __attribute__((ext_vector_type(4)));

__device__ __forceinline__ unsigned short f2bf(float f) {
  union { float f; unsigned int u; } v;
  v.f = f;
  unsigned int r = v.u + 0x7FFFu + ((v.u >> 16) & 1u);  // RNE
  return (unsigned short)(r >> 16);
}

__device__ __forceinline__ void load_lds16(const void* g, void* l) {
  __builtin_amdgcn_global_load_lds(
      (__attribute__((address_space(1))) void*)(void*)g,
      (__attribute__((address_space(3))) void*)l, 16, 0, 0);
}

// ---------- transpose + pad + pooled partials (round-5, best measured) ----------
__global__ void transpose_kernel(const float* __restrict__ x, unsigned short* __restrict__ xTpad,
                                 float* __restrict__ part) {
  int bid = blockIdx.x;
  int b = bid / 66, hp = bid % 66;
  unsigned short* rowbase = xTpad + ((size_t)(b * 66 + hp)) * 66 * 256;
  int t = threadIdx.x;
  if (hp == 0 || hp == 65) {
    uint4 z = make_uint4(0u, 0u, 0u, 0u);
    for (int i = t; i < 2112; i += 256) ((uint4*)rowbase)[i] = z;
    return;
  }
  int h = hp - 1;
  __shared__ unsigned short lds[64][264];
  __shared__ float psum[256];
  const float* xb = x + ((size_t)b * 256 * 64 + h) * 64;
  int lane = t & 63;
  #pragma unroll
  for (int g = 0; g < 16; ++g) {
    int c = g * 16 + (t >> 4);
    int w0 = (t & 15) * 4;
    float4 v = *(const float4*)&xb[(size_t)c * 4096 + w0];
    lds[w0 + 0][c] = f2bf(v.x);
    lds[w0 + 1][c] = f2bf(v.y);
    lds[w0 + 2][c] = f2bf(v.z);
    lds[w0 + 3][c] = f2bf(v.w);
    float s = v.x + v.y + v.z + v.w;
    s += __shfl_xor(s, 1); s += __shfl_xor(s, 2);
    s += __shfl_xor(s, 4); s += __shfl_xor(s, 8);
    if ((lane & 15) == 0) psum[c] = s;
  }
  __syncthreads();
  #pragma unroll
  for (int p = 0; p < 8; ++p) {
    int w = p * 8 + (t >> 5);
    int seg = t & 31;
    uint4 u = *(const uint4*)&lds[w][seg * 8];
    *(uint4*)&rowbase[(w + 1) * 256 + seg * 8] = u;
  }
  if (t < 64) {
    uint4 z = make_uint4(0u, 0u, 0u, 0u);
    int row = (t >> 5) ? 65 : 0;
    *(uint4*)&rowbase[row * 256 + (t & 31) * 8] = z;
  }
  if (t < 256) part[((size_t)b * 64 + h) * 256 + t] = psum[t];
}

// ---------- router (fp32 exact), 512 threads ----------
__global__ void router_kernel(
    const float* __restrict__ time_emb, const float* __restrict__ part,
    const float* __restrict__ Wq, const float* __restrict__ bq,
    const float* __restrict__ Wk, const float* __restrict__ bk,
    const float* __restrict__ Wv, const float* __restrict__ bv,
    const float* __restrict__ Wm1, const float* __restrict__ bm1,
    const float* __restrict__ Wm2, const float* __restrict__ bm2,
    const float* __restrict__ Wc, const float* __restrict__ bc,
    const float* __restrict__ expert_b,
    float* __restrict__ rw_out, float* __restrict__ beff_out) {
  int b = blockIdx.x, tid = threadIdx.x;
  int t = tid & 255;
  __shared__ float te[512], pl[256], qs[256], xa[256], m1s[64], xms[256], rws[4];
  te[tid] = time_emb[b * 512 + tid];
  if (tid < 256) {
    float s = 0.f;
    const float* pp = part + (size_t)b * 16384 + tid;
    for (int hh = 0; hh < 64; ++hh) s += pp[hh * 256];
    pl[tid] = s * (1.0f / 4096.0f);
  }
  __syncthreads();
  if (tid < 256) {
    float q = bq[t];
    const float4* wq4 = (const float4*)(Wq + (size_t)t * 512);
    #pragma unroll 4
    for (int i = 0; i < 128; ++i) {
      float4 w4 = wq4[i];
      q += w4.x * te[i*4] + w4.y * te[i*4+1] + w4.z * te[i*4+2] + w4.w * te[i*4+3];
    }
    qs[t] = q;
  } else {
    float k = bk[t], v = bv[t];
    const float4* wk4 = (const float4*)(Wk + (size_t)t * 256);
    const float4* wv4 = (const float4*)(Wv + (size_t)t * 256);
    #pragma unroll 4
    for (int i = 0; i < 64; ++i) {
      float4 a4 = wk4[i], b4 = wv4[i];
      float p0 = pl[i*4], p1 = pl[i*4+1], p2 = pl[i*4+2], p3 = pl[i*4+3];
      k += a4.x * p0 + a4.y * p1 + a4.z * p2 + a4.w * p3;
      v += b4.x * p0 + b4.y * p1 + b4.z * p2 + b4.w * p3;
    }
    xa[t] = k;
    xms[t] = v;
  }
  __syncthreads();
  if (tid < 256) {
    float k = xa[t], v = xms[t];
    float attn = 1.0f / (1.0f + expf(-(qs[t] * k)));
    qs[t] = v * attn;
  }
  __syncthreads();
  if (tid < 64) {
    float s = bm1[tid];
    const float4* w1 = (const float4*)(Wm1 + (size_t)tid * 256);
    #pragma unroll 4
    for (int i = 0; i < 64; ++i) {
      float4 w4 = w1[i];
      s += w4.x * qs[i*4] + w4.y * qs[i*4+1] + w4.z * qs[i*4+2] + w4.w * qs[i*4+3];
    }
    m1s[tid] = 0.5f * s * (1.0f + erff(s * 0.7071067811865476f));
  }
  __syncthreads();
  if (tid < 256) {
    float hsum = bm2[t];
    const float* w2 = Wm2 + (size_t)t * 64;
    for (int j = 0; j < 64; ++j) hsum += m1s[j] * w2[j];
    xms[t] = qs[t] + hsum;
  }
  __syncthreads();
  if (tid < 4) {
    float s = bc[tid];
    const float* wc = Wc + (size_t)tid * 256;
    for (int i = 0; i < 256; ++i) s += xms[i] * wc[i];
    float r = tanhf(s);
    rws[tid] = r;
    rw_out[b * 4 + tid] = r;
  }
  __syncthreads();
  if (tid < 256) {
    float be = 0.f;
    #pragma unroll
    for (int e = 0; e < 4; ++e) be += rws[e] * expert_b[e * 256 + t];
    beff_out[b * 256 + t] = be;
  }
}

// ---------- expert mix -> wmixT[b][ob][kc][o&15][k&7], coalesced both sides ----------
// kc = tap*32 + (c>>3). Block = (b, ob): stream 16 o-rows through lew (coalesced
// 1KB reads), scatter bf16 mix into obuf (fragment order), flush contiguous.
__global__ __launch_bounds__(256, 1) void wmixT_kernel(
    const float* __restrict__ ew, const float* __restrict__ rw,
    unsigned short* __restrict__ wmixT) {
  int b = blockIdx.x >> 4, ob = blockIdx.x & 15;
  int t = threadIdx.x;
  __shared__ float lew[4][2304];                 // 36.9 KB
  __shared__ unsigned short obuf[288 * 128];     // 72 KB
  float r0 = rw[b * 4 + 0], r1 = rw[b * 4 + 1], r2 = rw[b * 4 + 2], r3 = rw[b * 4 + 3];
  for (int op = 0; op < 16; ++op) {
    int o = ob * 16 + op;
    if (op) __syncthreads();                     // protect lew before overwrite
    #pragma unroll
    for (int e = 0; e < 4; ++e) {
      const float* s = ew + ((size_t)e * 256 + o) * 2304;
      #pragma unroll
      for (int j = 0; j < 9; ++j) lew[e][j * 256 + t] = s[j * 256 + t];
    }
    __syncthreads();
    // thread t owns c = t
    int base = (t >> 3) * 128 + op * 8 + (t & 7);
    #pragma unroll
    for (int tt = 0; tt < 9; ++tt) {
      float m = r0 * lew[0][t * 9 + tt] + r1 * lew[1][t * 9 + tt] +
                r2 * lew[2][t * 9 + tt] + r3 * lew[3][t * 9 + tt];
      obuf[tt * 32 * 128 + base] = f2bf(m);
    }
  }
  __syncthreads();
  // flush 72 KB contiguous
  uint4* dst = (uint4*)(wmixT + (size_t)(b * 16 + ob) * 288 * 128);
  const uint4* src = (const uint4*)obuf;
  #pragma unroll
  for (int i = 0; i < 18; ++i) dst[i * 256 + t] = src[i * 256 + t];
}

// ---------- conv: 256x256x2304 GEMM per sample (round-7 verbatim, 74.4 us) ----------
__global__ __launch_bounds__(512, 2) void conv_kernel(
    const unsigned short* __restrict__ xT, const unsigned short* __restrict__ wmixT,
    const float* __restrict__ beff, float* __restrict__ out) {
  __shared__ unsigned short Bs[2][16384];
  int bid = blockIdx.x;
  int b = ((bid & 7) << 1) | ((bid >> 7) & 1);   // same b -> same XCD
  int nt = (bid >> 3) & 15;
  int h0 = nt << 2;
  int tid = threadIdx.x;
  int wid = tid >> 6, lane = tid & 63;
  int lm = lane & 15, lg = lane >> 4;
  int wm = wid >> 1, wn = wid & 1;   // 4M x 2N wave grid

  const unsigned short* xTb = xT + (size_t)b * 66 * 66 * 256;
  const unsigned short* wmA = wmixT + (size_t)(b * 16 + wm * 4) * 288 * 128 + lane * 8;

  int lr = lane >> 3;
  int slot_g = (lane & 7) ^ lr;
  int b_lane = lr * 256 + slot_g * 8;

  int sw0 = ((0 + lg) ^ (lm & 7)) * 8;
  int sw1 = ((4 + lg) ^ (lm & 7)) * 8;

  auto stB = [&](int buf, int kh, int cc, int kw, int q) {
    const unsigned short* src =
        xTb + (size_t)((h0 + q + kh) * 66 + wid * 8 + kw) * 256 + cc * 64 + b_lane;
    load_lds16(src, &Bs[buf][(q * 64 + wid * 8) * 64]);
  };

  f32x4 acc[4][8];
  #pragma unroll
  for (int mf = 0; mf < 4; ++mf)
    #pragma unroll
    for (int nf = 0; nf < 8; ++nf)
      acc[mf][nf] = (f32x4){0.f, 0.f, 0.f, 0.f};

  bf16x8 Ae[4][2], Ao[4][2];

  stB(0, 0, 0, 0, 0); stB(0, 0, 0, 0, 1); stB(0, 0, 0, 0, 2); stB(0, 0, 0, 0, 3);
  __builtin_amdgcn_sched_barrier(0);
  #pragma unroll
  for (int mf = 0; mf < 4; ++mf)
    #pragma unroll
    for (int kk = 0; kk < 2; ++kk)
      Ae[mf][kk] = *(const bf16x8*)(wmA + (size_t)(mf * 288 + kk * 4) * 128);
  asm volatile("s_waitcnt vmcnt(8)" ::: "memory");
  __builtin_amdgcn_s_barrier();

  auto tile_body = [&](int t, int buf, bf16x8 (&Acur)[4][2], bf16x8 (&Anext)[4][2])
      __attribute__((always_inline)) {
    bool st = (t < 35);
    if (st) {
      int tn = t + 1;
      int khn = tn / 12, rn = tn % 12, ccn = rn / 3, kwn = rn % 3;
      stB(buf ^ 1, khn, ccn, kwn, 0); stB(buf ^ 1, khn, ccn, kwn, 1);
      stB(buf ^ 1, khn, ccn, kwn, 2); stB(buf ^ 1, khn, ccn, kwn, 3);
      __builtin_amdgcn_sched_barrier(0);   // keep gll ahead of A-loads in vmcnt FIFO
      int kbase = (khn * 3 + kwn) * 32 + ccn * 8;
      #pragma unroll
      for (int mf = 0; mf < 4; ++mf)
        #pragma unroll
        for (int kk = 0; kk < 2; ++kk)
          Anext[mf][kk] = *(const bf16x8*)(wmA + (size_t)(mf * 288 + kbase + kk * 4) * 128);
    }
    #pragma unroll
    for (int nf = 0; nf < 8; ++nf) {
      bf16x8 b0 = *(const bf16x8*)&Bs[buf][(wn * 128 + nf * 16 + lm) * 64 + sw0];
      bf16x8 b1 = *(const bf16x8*)&Bs[buf][(wn * 128 + nf * 16 + lm) * 64 + sw1];
      #pragma unroll
      for (int mf = 0; mf < 4; ++mf) {
        acc[mf][nf] = __builtin_amdgcn_mfma_f32_16x16x32_bf16(Acur[mf][0], b0, acc[mf][nf], 0, 0, 0);
        acc[mf][nf] = __builtin_amdgcn_mfma_f32_16x16x32_bf16(Acur[mf][1], b1, acc[mf][nf], 0, 0, 0);
      }
    }
    if (st) {
      asm volatile("s_waitcnt vmcnt(8)" ::: "memory");
      __builtin_amdgcn_s_barrier();
    }
  };

  for (int i = 0; i < 18; ++i) {
    tile_body(2 * i, 0, Ae, Ao);
    tile_body(2 * i + 1, 1, Ao, Ae);
  }

  #pragma unroll
  for (int mf = 0; mf < 4; ++mf) {
    int o = wm * 64 + mf * 16 + lg * 4;
    float be0 = beff[b * 256 + o + 0];
    float be1 = beff[b * 256 + o + 1];
    float be2 = beff[b * 256 + o + 2];
    float be3 = beff[b * 256 + o + 3];
    #pragma unroll
    for (int nf = 0; nf < 8; ++nf) {
      int n = wn * 128 + nf * 16 + lm;
      int hh = h0 + (n >> 6), w = n & 63;
      float* op = out + (((size_t)(b * 256 + o)) * 64 + hh) * 64 + w;
      op[0]            = acc[mf][nf][0] + be0;
      op[4096]         = acc[mf][nf][1] + be1;
      op[2 * 4096]     = acc[mf][nf][2] + be2;
      op[3 * 4096]     = acc[mf][nf][3] + be3;
    }
  }
}

extern "C" void kernel_launch(void* const* d_in, const int* in_sizes, int n_in,
                              void* d_out, int out_size, void* d_ws, size_t ws_size,
                              hipStream_t stream) {
  const float* x        = (const float*)d_in[0];
  const float* time_emb = (const float*)d_in[1];
  const float* Wq = (const float*)d_in[2];
  const float* bq = (const float*)d_in[3];
  const float* Wk = (const float*)d_in[4];
  const float* bk = (const float*)d_in[5];
  const float* Wv = (const float*)d_in[6];
  const float* bv = (const float*)d_in[7];
  const float* Wm1 = (const float*)d_in[8];
  const float* bm1 = (const float*)d_in[9];
  const float* Wm2 = (const float*)d_in[10];
  const float* bm2 = (const float*)d_in[11];
  const float* Wc = (const float*)d_in[12];
  const float* bc = (const float*)d_in[13];
  const float* expert_w = (const float*)d_in[14];
  const float* expert_b = (const float*)d_in[15];
  float* out = (float*)d_out;

  char* ws = (char*)d_ws;
  float* rw   = (float*)(ws + 0);
  float* beff = (float*)(ws + 1024);
  float* part = (float*)(ws + 20480);
  unsigned short* xTpad = (unsigned short*)(ws + 1069056);             // 35.7 MB
  unsigned short* wmixT = (unsigned short*)(ws + 1069056 + 35684352);  // 18.9 MB

  transpose_kernel<<<1056, 256, 0, stream>>>(x, xTpad, part);
  router_kernel<<<16, 512, 0, stream>>>(time_emb, part, Wq, bq, Wk, bk, Wv, bv,
                                        Wm1, bm1, Wm2, bm2, Wc, bc, expert_b, rw, beff);
  wmixT_kernel<<<256, 256, 0, stream>>>(expert_w, rw, wmixT);
  conv_kernel<<<256, 512, 0, stream>>>(xTpad, wmixT, beff, out);
}